// Round 1
// baseline (850.304 us; speedup 1.0000x reference)
//
#include <hip/hip_runtime.h>
#include <hip/hip_bf16.h>

typedef __bf16 bf16;
typedef __bf16 bf16x4 __attribute__((ext_vector_type(4)));
typedef __bf16 bf16x8 __attribute__((ext_vector_type(8)));
typedef float f32x4 __attribute__((ext_vector_type(4)));

#define NF 40
#define HW 256
#define TS 16            // output tile 16x16
#define XR 20            // x stage region 20x20
#define OR 18            // out1 region 18x18
#define KPAD 384         // 9 taps * 40 ci padded to 12*32
#define MPAD 48          // 40 co padded to 3*16

// Rearrange weights into MFMA A-matrix layout [co][k], bf16, zero-padded.
// ws layout: W3A[48*384] | W4A[48*384] | W2A[48*64]
__global__ void prep_weights(const float* __restrict__ w2,
                             const float* __restrict__ w3,
                             const float* __restrict__ w4,
                             bf16* __restrict__ ws) {
  int i = blockIdx.x * 256 + threadIdx.x;
  const int T = MPAD * KPAD;               // 18432
  if (i < T) {
    int co = i / KPAD, k = i % KPAD;
    float v3 = 0.f, v4 = 0.f;
    if (co < NF && k < 360) {
      int tap = k / NF, ci = k - tap * NF;
      int ky = tap / 3, kx = tap - ky * 3;
      int idx = ((co * NF + ci) * 3 + ky) * 3 + kx;
      v3 = w3[idx];
      v4 = w4[idx];
    }
    ws[i] = (bf16)v3;
    ws[T + i] = (bf16)v4;
  }
  if (i < MPAD * 64) {
    int co = i / 64, ci = i - co * 64;
    float v = 0.f;
    if (co < NF && ci < NF) v = w2[co * NF + ci];
    ws[2 * T + i] = (bf16)v;
  }
}

__global__ __launch_bounds__(512, 4)
void paconv_fused(const float* __restrict__ x,
                  const float* __restrict__ b2,
                  const bf16* __restrict__ ws,
                  float* __restrict__ out) {
  __shared__ bf16 xs[XR * XR * NF];        // 16000 elems = 32000 B, [y][x][ci]
  __shared__ bf16 o1[OR * OR * NF];        // 12960 elems = 25920 B, [y][x][co]

  const int tid  = threadIdx.x;
  const int lane = tid & 63;
  const int wid  = tid >> 6;               // 0..7
  const int l15  = lane & 15;
  const int lk   = lane >> 4;              // 0..3
  const int n    = blockIdx.z;
  const int X0   = blockIdx.x * TS;
  const int Y0   = blockIdx.y * TS;

  const bf16* W3A = ws;
  const bf16* W4A = ws + MPAD * KPAD;
  const bf16* W2A = ws + 2 * MPAD * KPAD;

  // ---- stage x region [Y0-2, Y0+18) x [X0-2, X0+18), transpose to ci-innermost
  const float* xn = x + (size_t)n * NF * HW * HW;
  for (int i = tid; i < XR * XR * NF; i += 512) {
    int ci  = i / (XR * XR);
    int rem = i - ci * (XR * XR);          // yy*XR + xx
    int yy  = rem / XR, xx = rem - yy * XR;
    int gy  = Y0 - 2 + yy, gx = X0 - 2 + xx;
    float v = 0.f;
    if ((unsigned)gy < HW && (unsigned)gx < HW)
      v = xn[(size_t)ci * HW * HW + gy * HW + gx];
    xs[rem * NF + ci] = (bf16)v;
  }

  // per-lane bias values: co = mt*16 + lk*4 + r
  float b2v[3][4];
#pragma unroll
  for (int mt = 0; mt < 3; ++mt)
#pragma unroll
    for (int r = 0; r < 4; ++r) {
      int co = mt * 16 + lk * 4 + r;
      b2v[mt][r] = (co < NF) ? b2[co] : 0.f;
    }

  __syncthreads();

  // ---- phase 1: out1 = sigmoid(conv1x1 + b) * conv3x3(w3) on 18x18 region
#pragma unroll
  for (int ni = 0; ni < 3; ++ni) {
    int nt = wid + ni * 8;
    if (nt < 21) {
      int pixr = nt * 16 + l15;            // real pixel id
      bool real = pixr < 324;
      int pix = real ? pixr : 323;         // clamp for address safety
      int py = pix / OR, px = pix - py * OR;
      int pixbase = (py * XR + px) * NF;

      f32x4 acc[3] = {f32x4{0,0,0,0}, f32x4{0,0,0,0}, f32x4{0,0,0,0}};
      f32x4 gacc[3] = {f32x4{0,0,0,0}, f32x4{0,0,0,0}, f32x4{0,0,0,0}};

      // conv3x3 GEMM: K = 360 padded to 384
#pragma unroll
      for (int kk = 0; kk < 12; ++kk) {
        int k0 = kk * 32 + lk * 8;
        int kc = (k0 < 360) ? k0 : 0;      // clamped addr; A rows are 0 there
        int tap = kc / NF, ci0 = kc - tap * NF;
        int ky = tap / 3, kx = tap - ky * 3;
        int off = (ky * XR + kx) * NF + ci0;
        bf16x8 b = *(const bf16x8*)&xs[pixbase + off];
#pragma unroll
        for (int mt = 0; mt < 3; ++mt) {
          bf16x8 a = *(const bf16x8*)&W3A[(mt * 16 + l15) * KPAD + k0];
          acc[mt] = __builtin_amdgcn_mfma_f32_16x16x32_bf16(a, b, acc[mt], 0, 0, 0);
        }
      }
      // gate 1x1 GEMM: K = 40 padded to 64, center tap of x
#pragma unroll
      for (int kk = 0; kk < 2; ++kk) {
        int k0 = kk * 32 + lk * 8;
        int cic = (k0 < NF) ? k0 : 0;
        bf16x8 b = *(const bf16x8*)&xs[pixbase + (XR + 1) * NF + cic];
#pragma unroll
        for (int mt = 0; mt < 3; ++mt) {
          bf16x8 a = *(const bf16x8*)&W2A[(mt * 16 + l15) * 64 + k0];
          gacc[mt] = __builtin_amdgcn_mfma_f32_16x16x32_bf16(a, b, gacc[mt], 0, 0, 0);
        }
      }

      // combine, zero outside image (conv4's zero padding), store to o1
      int gy1 = Y0 - 1 + py, gx1 = X0 - 1 + px;
      float keep = (((unsigned)gy1 < HW) && ((unsigned)gx1 < HW)) ? 1.f : 0.f;
      if (real) {
#pragma unroll
        for (int mt = 0; mt < 3; ++mt) {
          int co0 = mt * 16 + lk * 4;
          if (co0 < NF) {                  // skip padded co 40..47
            bf16x4 o;
#pragma unroll
            for (int r = 0; r < 4; ++r) {
              float g = 1.f / (1.f + __expf(-(gacc[mt][r] + b2v[mt][r])));
              o[r] = (bf16)(acc[mt][r] * g * keep);
            }
            *(bf16x4*)&o1[pix * NF + co0] = o;
          }
        }
      }
    }
  }

  __syncthreads();

  // ---- phase 2: out = conv3x3(out1, w4) on the 16x16 tile
  f32x4 acc2[2][3] = {{f32x4{0,0,0,0}, f32x4{0,0,0,0}, f32x4{0,0,0,0}},
                      {f32x4{0,0,0,0}, f32x4{0,0,0,0}, f32x4{0,0,0,0}}};
#pragma unroll
  for (int t2 = 0; t2 < 2; ++t2) {
    int oy = wid * 2 + t2;                 // 0..15
    int ox = l15;
    int pixbase2 = (oy * OR + ox) * NF;
#pragma unroll
    for (int kk = 0; kk < 12; ++kk) {
      int k0 = kk * 32 + lk * 8;
      int kc = (k0 < 360) ? k0 : 0;
      int tap = kc / NF, ci0 = kc - tap * NF;
      int ky = tap / 3, kx = tap - ky * 3;
      int off = (ky * OR + kx) * NF + ci0;
      bf16x8 b = *(const bf16x8*)&o1[pixbase2 + off];
#pragma unroll
      for (int mt = 0; mt < 3; ++mt) {
        bf16x8 a = *(const bf16x8*)&W4A[(mt * 16 + l15) * KPAD + k0];
        acc2[t2][mt] = __builtin_amdgcn_mfma_f32_16x16x32_bf16(a, b, acc2[t2][mt], 0, 0, 0);
      }
    }
  }

  // store f32 NCHW
  float* on = out + (size_t)n * NF * HW * HW;
#pragma unroll
  for (int t2 = 0; t2 < 2; ++t2) {
    int oy = wid * 2 + t2;
    int ox = l15;
#pragma unroll
    for (int mt = 0; mt < 3; ++mt) {
#pragma unroll
      for (int r = 0; r < 4; ++r) {
        int co = mt * 16 + lk * 4 + r;
        if (co < NF)
          on[(size_t)co * HW * HW + (Y0 + oy) * HW + (X0 + ox)] = acc2[t2][mt][r];
      }
    }
  }
}

extern "C" void kernel_launch(void* const* d_in, const int* in_sizes, int n_in,
                              void* d_out, int out_size, void* d_ws, size_t ws_size,
                              hipStream_t stream) {
  const float* x  = (const float*)d_in[0];
  const float* w2 = (const float*)d_in[1];
  const float* b2 = (const float*)d_in[2];
  const float* w3 = (const float*)d_in[3];
  const float* w4 = (const float*)d_in[4];
  float* out = (float*)d_out;
  bf16* ws   = (bf16*)d_ws;

  hipLaunchKernelGGL(prep_weights, dim3(72), dim3(256), 0, stream, w2, w3, w4, ws);
  hipLaunchKernelGGL(paconv_fused, dim3(16, 16, 16), dim3(512), 0, stream,
                     x, b2, ws, out);
}

// Round 2
// 425.249 us; speedup vs baseline: 1.9995x; 1.9995x over previous
//
#include <hip/hip_runtime.h>
#include <hip/hip_bf16.h>

typedef __bf16 bf16;
typedef __bf16 bf16x2 __attribute__((ext_vector_type(2)));
typedef __bf16 bf16x4 __attribute__((ext_vector_type(4)));
typedef __bf16 bf16x8 __attribute__((ext_vector_type(8)));
typedef float f32x4 __attribute__((ext_vector_type(4)));

#define NF 40
#define HW 256
#define TS 16            // output tile 16x16
#define XR 20            // x stage region 20x20
#define OR 18            // out1 region 18x18
#define KPAD 384         // 9 taps * 40 ci padded to 12*32
#define MPAD 48          // 40 co padded to 3*16

// Rearrange weights into MFMA A-matrix layout [co][k], bf16, zero-padded.
// ws layout: W3A[48*384] | W4A[48*384] | W2A[48*64]
__global__ void prep_weights(const float* __restrict__ w2,
                             const float* __restrict__ w3,
                             const float* __restrict__ w4,
                             bf16* __restrict__ ws) {
  int i = blockIdx.x * 256 + threadIdx.x;
  const int T = MPAD * KPAD;               // 18432
  if (i < T) {
    int co = i / KPAD, k = i % KPAD;
    float v3 = 0.f, v4 = 0.f;
    if (co < NF && k < 360) {
      int tap = k / NF, ci = k - tap * NF;
      int ky = tap / 3, kx = tap - ky * 3;
      int idx = ((co * NF + ci) * 3 + ky) * 3 + kx;
      v3 = w3[idx];
      v4 = w4[idx];
    }
    ws[i] = (bf16)v3;
    ws[T + i] = (bf16)v4;
  }
  if (i < MPAD * 64) {
    int co = i / 64, ci = i - co * 64;
    float v = 0.f;
    if (co < NF && ci < NF) v = w2[co * NF + ci];
    ws[2 * T + i] = (bf16)v;
  }
}

__global__ __launch_bounds__(512, 4)
void paconv_fused(const float* __restrict__ x,
                  const float* __restrict__ b2,
                  const bf16* __restrict__ ws,
                  float* __restrict__ out) {
  __shared__ bf16 xs[XR * XR * NF];        // 32000 B, [y][x][ci]
  __shared__ bf16 o1[OR * OR * NF];        // 25920 B, [y][x][co]; gate then out1

  const int tid  = threadIdx.x;
  const int lane = tid & 63;
  const int wid  = tid >> 6;               // 0..7
  const int l15  = lane & 15;
  const int lk   = lane >> 4;              // 0..3
  const int n    = blockIdx.z;
  const int X0   = blockIdx.x * TS;
  const int Y0   = blockIdx.y * TS;

  const bf16* W3A = ws;
  const bf16* W4A = ws + MPAD * KPAD;
  const bf16* W2A = ws + 2 * MPAD * KPAD;

  // ---- stage x region [Y0-2, Y0+18) x [X0-2, X0+18), ci-innermost, ci-pairs
  const float* xn = x + (size_t)n * NF * HW * HW;
  for (int i = tid; i < XR * XR * NF / 2; i += 512) {
    int cih = i / (XR * XR);
    int rem = i - cih * (XR * XR);         // yy*XR + xx
    int ci  = cih * 2;
    int yy  = rem / XR, xx = rem - yy * XR;
    int gy  = Y0 - 2 + yy, gx = X0 - 2 + xx;
    float v0 = 0.f, v1 = 0.f;
    if ((unsigned)gy < HW && (unsigned)gx < HW) {
      const float* p = xn + (size_t)ci * HW * HW + gy * HW + gx;
      v0 = p[0];
      v1 = p[HW * HW];
    }
    bf16x2 pr; pr[0] = (bf16)v0; pr[1] = (bf16)v1;
    *(bf16x2*)&xs[rem * NF + ci] = pr;
  }

  // ---- per-lane precompute (once; no divs in inner loops)
  int off3[12];
#pragma unroll
  for (int kk = 0; kk < 12; ++kk) {
    int k0 = kk * 32 + lk * 8;
    int kc = (k0 < 360) ? k0 : 0;          // A rows are zero past 360
    int tap = kc / NF, ci0 = kc - tap * NF;
    int ky = tap / 3, kx = tap - ky * 3;
    off3[kk] = (ky * XR + kx) * NF + ci0;
  }

  int pb[3], pixv[3];
  float keepv[3];
  bool realv[3];
#pragma unroll
  for (int ni = 0; ni < 3; ++ni) {
    int nt   = wid + ni * 8;
    int pixr = nt * 16 + l15;
    bool real = pixr < 324;
    int pix  = real ? pixr : 323;
    int py = pix / OR, px = pix - py * OR;
    pb[ni]   = (py * XR + px) * NF;
    pixv[ni] = pix;
    realv[ni] = real;
    int gy1 = Y0 - 1 + py, gx1 = X0 - 1 + px;
    keepv[ni] = (((unsigned)gy1 < HW) && ((unsigned)gx1 < HW)) ? 1.f : 0.f;
  }

  __syncthreads();

  // ---- gate pass: sigma(conv1x1 + b) -> o1 (bf16), lane-private cells
  {
    float b2v[3][4];
#pragma unroll
    for (int mt = 0; mt < 3; ++mt)
#pragma unroll
      for (int r = 0; r < 4; ++r) {
        int co = mt * 16 + lk * 4 + r;
        b2v[mt][r] = (co < NF) ? b2[co] : 0.f;
      }
    int goff[2];
#pragma unroll
    for (int kk = 0; kk < 2; ++kk) {
      int k0 = kk * 32 + lk * 8;
      goff[kk] = (XR + 1) * NF + ((k0 < NF) ? k0 : 0);
    }
    bf16x8 a2[2][3];
#pragma unroll
    for (int kk = 0; kk < 2; ++kk)
#pragma unroll
      for (int mt = 0; mt < 3; ++mt)
        a2[kk][mt] = *(const bf16x8*)&W2A[(mt * 16 + l15) * 64 + kk * 32 + lk * 8];

#pragma unroll
    for (int ni = 0; ni < 3; ++ni) {
      f32x4 g[3] = {f32x4{0,0,0,0}, f32x4{0,0,0,0}, f32x4{0,0,0,0}};
#pragma unroll
      for (int kk = 0; kk < 2; ++kk) {
        bf16x8 b = *(const bf16x8*)&xs[pb[ni] + goff[kk]];
#pragma unroll
        for (int mt = 0; mt < 3; ++mt)
          g[mt] = __builtin_amdgcn_mfma_f32_16x16x32_bf16(a2[kk][mt], b, g[mt], 0, 0, 0);
      }
      if (realv[ni]) {
#pragma unroll
        for (int mt = 0; mt < 3; ++mt) {
          int co0 = mt * 16 + lk * 4;
          if (co0 < NF) {
            bf16x4 gv;
#pragma unroll
            for (int r = 0; r < 4; ++r)
              gv[r] = (bf16)(1.f / (1.f + __expf(-(g[mt][r] + b2v[mt][r]))));
            *(bf16x4*)&o1[pixv[ni] * NF + co0] = gv;
          }
        }
      }
    }
  }

  // ---- main W3 pass: A-frags register-resident in kk-quarters
  {
    f32x4 facc[3][3];
#pragma unroll
    for (int ni = 0; ni < 3; ++ni)
#pragma unroll
      for (int mt = 0; mt < 3; ++mt)
        facc[ni][mt] = f32x4{0, 0, 0, 0};

#pragma unroll
    for (int q = 0; q < 4; ++q) {
      bf16x8 a3[3][3];
#pragma unroll
      for (int kk = 0; kk < 3; ++kk)
#pragma unroll
        for (int mt = 0; mt < 3; ++mt)
          a3[kk][mt] = *(const bf16x8*)
              &W3A[(mt * 16 + l15) * KPAD + (q * 3 + kk) * 32 + lk * 8];
#pragma unroll
      for (int ni = 0; ni < 3; ++ni)
#pragma unroll
        for (int kk = 0; kk < 3; ++kk) {
          bf16x8 b = *(const bf16x8*)&xs[pb[ni] + off3[q * 3 + kk]];
#pragma unroll
          for (int mt = 0; mt < 3; ++mt)
            facc[ni][mt] = __builtin_amdgcn_mfma_f32_16x16x32_bf16(
                a3[kk][mt], b, facc[ni][mt], 0, 0, 0);
        }
    }

    // epilogue: out1 = facc * gate * keep  (same lane as gate write — no sync)
#pragma unroll
    for (int ni = 0; ni < 3; ++ni) {
      if (realv[ni]) {
#pragma unroll
        for (int mt = 0; mt < 3; ++mt) {
          int co0 = mt * 16 + lk * 4;
          if (co0 < NF) {
            bf16x4 gv = *(const bf16x4*)&o1[pixv[ni] * NF + co0];
            bf16x4 ov;
#pragma unroll
            for (int r = 0; r < 4; ++r)
              ov[r] = (bf16)(facc[ni][mt][r] * (float)gv[r] * keepv[ni]);
            *(bf16x4*)&o1[pixv[ni] * NF + co0] = ov;
          }
        }
      }
    }
  }

  __syncthreads();

  // ---- phase 2: out = conv3x3(out1, w4)
  {
    int off4[12];
#pragma unroll
    for (int kk = 0; kk < 12; ++kk) {
      int k0 = kk * 32 + lk * 8;
      int kc = (k0 < 360) ? k0 : 0;
      int tap = kc / NF, ci0 = kc - tap * NF;
      int ky = tap / 3, kx = tap - ky * 3;
      off4[kk] = (ky * OR + kx) * NF + ci0;
    }
    int pb2[2];
#pragma unroll
    for (int t2 = 0; t2 < 2; ++t2)
      pb2[t2] = ((wid * 2 + t2) * OR + l15) * NF;

    f32x4 acc2[2][3];
#pragma unroll
    for (int t2 = 0; t2 < 2; ++t2)
#pragma unroll
      for (int mt = 0; mt < 3; ++mt)
        acc2[t2][mt] = f32x4{0, 0, 0, 0};

#pragma unroll
    for (int q = 0; q < 4; ++q) {
      bf16x8 a4[3][3];
#pragma unroll
      for (int kk = 0; kk < 3; ++kk)
#pragma unroll
        for (int mt = 0; mt < 3; ++mt)
          a4[kk][mt] = *(const bf16x8*)
              &W4A[(mt * 16 + l15) * KPAD + (q * 3 + kk) * 32 + lk * 8];
#pragma unroll
      for (int t2 = 0; t2 < 2; ++t2)
#pragma unroll
        for (int kk = 0; kk < 3; ++kk) {
          bf16x8 b = *(const bf16x8*)&o1[pb2[t2] + off4[q * 3 + kk]];
#pragma unroll
          for (int mt = 0; mt < 3; ++mt)
            acc2[t2][mt] = __builtin_amdgcn_mfma_f32_16x16x32_bf16(
                a4[kk][mt], b, acc2[t2][mt], 0, 0, 0);
        }
    }

    // store f32 NCHW
    float* on = out + (size_t)n * NF * HW * HW;
#pragma unroll
    for (int t2 = 0; t2 < 2; ++t2) {
      int oy = wid * 2 + t2;
#pragma unroll
      for (int mt = 0; mt < 3; ++mt)
#pragma unroll
        for (int r = 0; r < 4; ++r) {
          int co = mt * 16 + lk * 4 + r;
          if (co < NF)
            on[(size_t)co * HW * HW + (Y0 + oy) * HW + (X0 + l15)] = acc2[t2][mt][r];
        }
    }
  }
}

extern "C" void kernel_launch(void* const* d_in, const int* in_sizes, int n_in,
                              void* d_out, int out_size, void* d_ws, size_t ws_size,
                              hipStream_t stream) {
  const float* x  = (const float*)d_in[0];
  const float* w2 = (const float*)d_in[1];
  const float* b2 = (const float*)d_in[2];
  const float* w3 = (const float*)d_in[3];
  const float* w4 = (const float*)d_in[4];
  float* out = (float*)d_out;
  bf16* ws   = (bf16*)d_ws;

  hipLaunchKernelGGL(prep_weights, dim3(72), dim3(256), 0, stream, w2, w3, w4, ws);
  hipLaunchKernelGGL(paconv_fused, dim3(16, 16, 16), dim3(512), 0, stream,
                     x, b2, ws, out);
}